// Round 8
// baseline (268.081 us; speedup 1.0000x reference)
//
#include <hip/hip_runtime.h>
#include <math.h>

// CapsuleLayer dynamic routing, fp32 in/out. B=256, I=2048, K=8, J=10, D=16.
// R12: exact R6 champion kernels (139.9us: 128 chunks, 512 blocks, LDS double
// buffer, 8B p stores, vT [j][d][b]) + rs fused into round TAILS via a
// completion COUNTER (not a barrier): after p-stores drain, every block does
// threadfence + RELEASE atomic inc and 352/512 blocks EXIT; the 160 rs blocks
// spin with ACQUIRE polls throttled by s_sleep(16) (~0.4us/poll; R10's 85us/
// barrier pathology = unthrottled acquire polls -> continuous L2 invalidation).
// 7 launches -> 4 (pre + 3 rounds). rs red[] aliases dead L[1].
// Round core math unchanged (mfma_f32_16x16x32_bf16, C/D col=lane&15=b,
// row=(lane>>4)*4+reg=d; round 1 packs 4 i's into K=32).
//
// ws: bar u32[16] | vT f32[40960] | p f16[16*128*2560] | xTb bf16 | Wb bf16 (~24.3 MB)

#define BB 256
#define II 2048
#define KK 8
#define JJ 10
#define DD 16

typedef __attribute__((ext_vector_type(4))) float f32x4;
typedef __attribute__((ext_vector_type(8))) short short8;

__device__ __forceinline__ short f2bf(float f) {
    union { float f; unsigned u; } v; v.f = f;
    unsigned r = v.u + 0x7FFFu + ((v.u >> 16) & 1u);   // RNE
    return (short)(r >> 16);
}

// Fused preprocessing:
//   blocks [0,1280): W fp32 [j,i,d,k] -> Wb bf16 same layout (k contiguous).
//   blocks [1280,3328): x fp32 [b,i,k] -> xTb bf16 [i,b,k], LDS transpose tile.
__global__ __launch_bounds__(256) void pre_kernel(const float* __restrict__ x,
                                                  const float* __restrict__ W,
                                                  short* __restrict__ xTb,
                                                  short* __restrict__ Wb) {
    __shared__ float4 tile[8 * 66];
    const int t = threadIdx.x;
    const int bid = blockIdx.x;
    if (bid < 1280) {
        const int idx = bid * 256 + t;
        const float4* src = (const float4*)(W + (size_t)idx * 8);
        const float4 a = src[0], b = src[1];
        short8 o;
        o[0] = f2bf(a.x); o[1] = f2bf(a.y); o[2] = f2bf(a.z); o[3] = f2bf(a.w);
        o[4] = f2bf(b.x); o[5] = f2bf(b.y); o[6] = f2bf(b.z); o[7] = f2bf(b.w);
        *(short8*)(Wb + (size_t)idx * 8) = o;
    } else {
        const int bb = bid - 1280;
        const int b0 = (bb >> 8) * 32, i0 = (bb & 255) * 8;
        {
            const int lb = t >> 3, li = t & 7;
            const float4* src = (const float4*)(x + ((b0 + lb) * II + (i0 + li)) * KK);
            tile[li * 66 + lb * 2 + 0] = src[0];
            tile[li * 66 + lb * 2 + 1] = src[1];
        }
        __syncthreads();
        {
            const int ri = t >> 5, rb = t & 31;
            const float4 p0 = tile[ri * 66 + rb * 2 + 0];
            const float4 p1 = tile[ri * 66 + rb * 2 + 1];
            short8 o;
            o[0] = f2bf(p0.x); o[1] = f2bf(p0.y); o[2] = f2bf(p0.z); o[3] = f2bf(p0.w);
            o[4] = f2bf(p1.x); o[5] = f2bf(p1.y); o[6] = f2bf(p1.z); o[7] = f2bf(p1.w);
            *(short8*)(xTb + ((size_t)(i0 + ri) * BB + (b0 + rb)) * KK) = o;
        }
    }
}

// ---- staging helpers: 28 segments of 1024B per 8-i sub-chunk (20 W halves + 8 x rows) ----
// LDS layout per buffer (shorts): Wl[j][il][d][k] at j*1024+il*128+d*8 ; Xl at 10240+il*512+b*8
#define LBUF 14336   // shorts per buffer

__device__ __forceinline__ void seg_src_dst(int s, int i0, int b0,
                                            const short* __restrict__ xTb,
                                            const short* __restrict__ Wb,
                                            const short** src, int* dst) {
    if (s < 20) {
        const int j = s >> 1, h = s & 1;
        *src = Wb + ((size_t)(j * II + i0) * DD) * KK + h * 512;
        *dst = j * 1024 + h * 512;
    } else {
        const int il = s - 20;
        *src = xTb + ((size_t)(i0 + il) * BB + b0) * KK;
        *dst = 10240 + il * 512;
    }
}

// One routing round + fused rs tail. grid (128, 4), block 256 (4 waves = 4
// b-tiles). i-chunk 16 = 2 sub-chunks of 8, LDS double-buffer, reg prefetch.
// Partials p[bt][chunk][j*64+lane] (4 fp16/lane, 8B stores) -- R6 layout.
// Tail: release-count on bar[MODE]; blocks fbid>=160 exit; 160 rs blocks
// (j=fbid>>4, btq=fbid&15) spin (acquire, s_sleep-throttled) until 512, then
// reduce+squash (R6 rs body, red aliased in L[1]).
// MODE 0: vT = squash(0.1*s)  MODE 1: vT += squash(s)  MODE 2: out = squash(s)
template <int USE_C, int MODE>
__global__ __launch_bounds__(256) void round_mfma(
    const short* __restrict__ xTb, const short* __restrict__ Wb,
    float* __restrict__ vT, _Float16* __restrict__ p, float* __restrict__ out,
    unsigned* __restrict__ bar)
{
    __shared__ short L[2][LBUF];
    const int t = threadIdx.x;
    const int lane = t & 63, wv = t >> 6;
    const int col = lane & 15, q = lane >> 4;
    const int chunk = blockIdx.x;
    const int ytile = blockIdx.y;
    const int b0 = ytile * 64;
    const int bl = wv * 16 + col;          // b within block for this wave's tile
    const int i0 = chunk * 16;

    // ---- stage sub-chunk 0, prefetch sub-chunk 1 into regs ----
    short8 r0[7], r1[7];
#pragma unroll
    for (int n = 0; n < 7; ++n) {
        const int s = wv + n * 4;          // 4 waves interleave the 28 segments
        const short* src; int dst;
        seg_src_dst(s, i0, b0, xTb, Wb, &src, &dst);
        r0[n] = *(const short8*)(src + lane * 8);
        seg_src_dst(s, i0 + 8, b0, xTb, Wb, &src, &dst);
        r1[n] = *(const short8*)(src + lane * 8);
    }
#pragma unroll
    for (int n = 0; n < 7; ++n) {
        const int s = wv + n * 4;
        const short* src; int dst;
        seg_src_dst(s, i0, b0, xTb, Wb, &src, &dst);
        *(short8*)(&L[0][dst + lane * 8]) = r0[n];
    }
    __syncthreads();

    f32x4 sfrag[JJ];
#pragma unroll
    for (int j = 0; j < JJ; ++j) sfrag[j] = (f32x4){0.f, 0.f, 0.f, 0.f};

    float vfrag[JJ][4];
    if (USE_C) {
#pragma unroll
        for (int j = 0; j < JJ; ++j)
#pragma unroll
            for (int r = 0; r < 4; ++r)
                vfrag[j][r] = vT[(j * DD + q * 4 + r) * BB + b0 + bl];
    }

#pragma unroll
    for (int sc = 0; sc < 2; ++sc) {
        const short* Lb = L[sc];
        if (USE_C) {
            for (int il = 0; il < 8; ++il) {
                short8 A[JJ], Bf;
                const short8 z = (short8){0, 0, 0, 0, 0, 0, 0, 0};
                Bf = z;
#pragma unroll
                for (int j = 0; j < JJ; ++j) A[j] = z;
                if (q == 0) {   // kc 0..7 real, quads 1..3 stay zero (k-pad 8->32)
                    Bf = *(const short8*)(&Lb[10240 + il * 512 + bl * 8]);
#pragma unroll
                    for (int j = 0; j < JJ; ++j)
                        A[j] = *(const short8*)(&Lb[j * 1024 + il * 128 + col * 8]);
                }
                f32x4 U[JJ];
#pragma unroll
                for (int j = 0; j < JJ; ++j)
                    U[j] = __builtin_amdgcn_mfma_f32_16x16x32_bf16(
                        A[j], Bf, (f32x4){0.f, 0.f, 0.f, 0.f}, 0, 0, 0);
                float Lg[JJ];
#pragma unroll
                for (int j = 0; j < JJ; ++j)
                    Lg[j] = vfrag[j][0] * U[j][0] + vfrag[j][1] * U[j][1]
                          + vfrag[j][2] * U[j][2] + vfrag[j][3] * U[j][3];
#pragma unroll
                for (int j = 0; j < JJ; ++j) {   // reduce over the 4 d-quads
                    Lg[j] += __shfl_xor(Lg[j], 16, 64);
                    Lg[j] += __shfl_xor(Lg[j], 32, 64);
                }
                float sum = 0.f;   // |logit| is O(1): no max-subtraction needed
#pragma unroll
                for (int j = 0; j < JJ; ++j) { Lg[j] = __expf(Lg[j]); sum += Lg[j]; }
                const float inv = __builtin_amdgcn_rcpf(sum);
#pragma unroll
                for (int j = 0; j < JJ; ++j) {
                    const float c = Lg[j] * inv;
#pragma unroll
                    for (int r = 0; r < 4; ++r) sfrag[j][r] += c * U[j][r];
                }
            }
        } else {
            // round 1: sum_i U. Pack 4 i's per MFMA: kc = q*8 + k -> i_local = q.
#pragma unroll
            for (int s = 0; s < 2; ++s) {
                const int il = s * 4 + q;
                const short8 Bf = *(const short8*)(&Lb[10240 + il * 512 + bl * 8]);
#pragma unroll
                for (int j = 0; j < JJ; ++j) {
                    const short8 A = *(const short8*)(&Lb[j * 1024 + il * 128 + col * 8]);
                    sfrag[j] = __builtin_amdgcn_mfma_f32_16x16x32_bf16(A, Bf, sfrag[j], 0, 0, 0);
                }
            }
        }
        if (sc == 0) {   // publish sub-chunk 1 (regs were loaded before compute 0)
#pragma unroll
            for (int n = 0; n < 7; ++n) {
                const int s = wv + n * 4;
                const short* src; int dst;
                seg_src_dst(s, i0 + 8, b0, xTb, Wb, &src, &dst);
                *(short8*)(&L[1][dst + lane * 8]) = r1[n];
            }
            __syncthreads();
        }
    }

    // epilogue: wave-private partial chunk, 10 coalesced 8B stores (R6 exact)
    _Float16* pp = p + ((size_t)(ytile * 4 + wv) * 128 + chunk) * (JJ * 256);
#pragma unroll
    for (int j = 0; j < JJ; ++j) {
        union { uint2 u; _Float16 h[4]; } pk;
        pk.h[0] = (_Float16)sfrag[j][0];
        pk.h[1] = (_Float16)sfrag[j][1];
        pk.h[2] = (_Float16)sfrag[j][2];
        pk.h[3] = (_Float16)sfrag[j][3];
        *(uint2*)(pp + (size_t)(j * 64 + lane) * 4) = pk.u;
    }

    // ---- completion count: all blocks arrive; only 160 rs blocks wait ----
    const int fbid = blockIdx.y * 128 + blockIdx.x;
    __syncthreads();   // drains vmcnt(0): all 4 waves' p stores retired
    if (t == 0) {
        __threadfence();   // L2 writeback so cross-XCD readers see p
        __hip_atomic_fetch_add(&bar[MODE], 1u, __ATOMIC_RELEASE,
                               __HIP_MEMORY_SCOPE_AGENT);
    }
    if (fbid >= JJ * 16) return;   // 352 blocks exit, freeing the machine

    if (t == 0) {
        // throttled acquire-poll (R10 lesson: unthrottled acquire spin =
        // continuous L2 invalidation device-wide)
        while (__hip_atomic_load(&bar[MODE], __ATOMIC_ACQUIRE,
                                 __HIP_MEMORY_SCOPE_AGENT) < 512u)
            __builtin_amdgcn_s_sleep(16);
        __threadfence();
    }
    __syncthreads();

    // ---- rs: reduce 128 chunks + squash (R6 rs body; red aliases L[1]) ----
    {
        const int j = fbid >> 4, btq = fbid & 15;
        const int eg = t & 63, cgi = t >> 6;
        f32x4* red = (f32x4*)(&L[1][0]);
        const _Float16* prd = p + ((size_t)btq * 128 + cgi * 32) * (JJ * 256)
                            + j * 256 + eg * 4;
        float s0 = 0.f, s1 = 0.f, s2 = 0.f, s3 = 0.f;
#pragma unroll 8
        for (int ch = 0; ch < 32; ++ch) {
            union { uint2 u; _Float16 h[4]; } cv;
            cv.u = *(const uint2*)(prd + (size_t)ch * (JJ * 256));
            s0 += (float)cv.h[0]; s1 += (float)cv.h[1];
            s2 += (float)cv.h[2]; s3 += (float)cv.h[3];
        }
        red[t] = (f32x4){s0, s1, s2, s3};
        __syncthreads();
        if (t < 64) {
            f32x4 a = red[t];
            a += red[64 + t]; a += red[128 + t]; a += red[192 + t];
            const float scale = (MODE == 0) ? 0.1f : 1.0f;
            const float x0 = a[0] * scale, x1 = a[1] * scale;
            const float x2 = a[2] * scale, x3 = a[3] * scale;
            float ss = x0 * x0 + x1 * x1 + x2 * x2 + x3 * x3;
            ss += __shfl_xor(ss, 16, 64);   // sum over the 4 d-quads (same bc)
            ss += __shfl_xor(ss, 32, 64);
            const float coef = ss / (1.f + ss) / sqrtf(ss + 1e-7f);
            const int qd = t >> 4, bc = t & 15;
            const float v[4] = {coef * x0, coef * x1, coef * x2, coef * x3};
#pragma unroll
            for (int r = 0; r < 4; ++r) {
                const int d = qd * 4 + r;
                if (MODE == 0) vT[(j * DD + d) * BB + btq * 16 + bc] = v[r];
                if (MODE == 1) vT[(j * DD + d) * BB + btq * 16 + bc] += v[r];
                if (MODE == 2) out[((btq * 16 + bc) * JJ + j) * DD + d] = v[r];
            }
        }
    }
}

// ---------------- fallback path (round-1 passing kernel, 365us) ----------------
#define IT_OLD 32
#define BT_OLD 16

__global__ __launch_bounds__(256) void zero_kernel(float* __restrict__ p, int n) {
    int idx = blockIdx.x * blockDim.x + threadIdx.x;
    if (idx < n) p[idx] = 0.f;
}

__global__ __launch_bounds__(256) void squash_old(float* __restrict__ s_acc,
                                                  float* __restrict__ dst, float scale,
                                                  int add_to_dst, int zero_src) {
    int idx = blockIdx.x * blockDim.x + threadIdx.x;
    if (idx >= BB * JJ) return;
    float s[DD];
    float ss = 0.f;
#pragma unroll
    for (int d = 0; d < DD; ++d) {
        s[d] = s_acc[idx * DD + d] * scale;
        ss += s[d] * s[d];
    }
    const float coef = ss / (1.f + ss) / sqrtf(ss + 1e-7f);
#pragma unroll
    for (int d = 0; d < DD; ++d) {
        const float vv = coef * s[d];
        if (add_to_dst) dst[idx * DD + d] += vv;
        else            dst[idx * DD + d] = vv;
        if (zero_src)   s_acc[idx * DD + d] = 0.f;
    }
}

__global__ __launch_bounds__(256) void round1_old(const float* __restrict__ x,
                                                  const float* __restrict__ W,
                                                  float* __restrict__ s_acc) {
    const int t = threadIdx.x;
    const int d = t & 15;
    const int bq = t >> 4;
    const int b = blockIdx.y * BT_OLD + bq;
    const int i0 = blockIdx.x * IT_OLD;
    float acc[JJ];
#pragma unroll
    for (int j = 0; j < JJ; ++j) acc[j] = 0.f;
    for (int ii = 0; ii < IT_OLD; ++ii) {
        const int i = i0 + ii;
        const float* xp = x + ((b * II) + i) * KK;
        const float4 xa = *(const float4*)(xp);
        const float4 xb = *(const float4*)(xp + 4);
#pragma unroll
        for (int j = 0; j < JJ; ++j) {
            const float* wp = W + (((j * II + i) * DD + d) * KK);
            const float4 w0 = *(const float4*)(wp);
            const float4 w1 = *(const float4*)(wp + 4);
            acc[j] += w0.x*xa.x + w0.y*xa.y + w0.z*xa.z + w0.w*xa.w
                    + w1.x*xb.x + w1.y*xb.y + w1.z*xb.z + w1.w*xb.w;
        }
    }
#pragma unroll
    for (int j = 0; j < JJ; ++j)
        atomicAdd(&s_acc[(b * JJ + j) * DD + d], acc[j]);
}

__global__ __launch_bounds__(256) void round_old(const float* __restrict__ x,
                                                 const float* __restrict__ W,
                                                 const float* __restrict__ v,
                                                 float* __restrict__ s_acc) {
    const int t = threadIdx.x;
    const int d = t & 15;
    const int bq = t >> 4;
    const int b = blockIdx.y * BT_OLD + bq;
    const int i0 = blockIdx.x * IT_OLD;
    float vr[JJ], acc[JJ];
#pragma unroll
    for (int j = 0; j < JJ; ++j) {
        vr[j] = v[(b * JJ + j) * DD + d];
        acc[j] = 0.f;
    }
    for (int ii = 0; ii < IT_OLD; ++ii) {
        const int i = i0 + ii;
        const float* xp = x + ((b * II) + i) * KK;
        const float4 xa = *(const float4*)(xp);
        const float4 xb = *(const float4*)(xp + 4);
        float U[JJ], Lg[JJ];
#pragma unroll
        for (int j = 0; j < JJ; ++j) {
            const float* wp = W + (((j * II + i) * DD + d) * KK);
            const float4 w0 = *(const float4*)(wp);
            const float4 w1 = *(const float4*)(wp + 4);
            U[j] = w0.x*xa.x + w0.y*xa.y + w0.z*xa.z + w0.w*xa.w
                 + w1.x*xb.x + w1.y*xb.y + w1.z*xb.z + w1.w*xb.w;
            Lg[j] = vr[j] * U[j];
        }
#pragma unroll
        for (int m = 8; m >= 1; m >>= 1) {
#pragma unroll
            for (int j = 0; j < JJ; ++j) Lg[j] += __shfl_xor(Lg[j], m, 64);
        }
        float mx = Lg[0];
#pragma unroll
        for (int j = 1; j < JJ; ++j) mx = fmaxf(mx, Lg[j]);
        float sum = 0.f;
#pragma unroll
        for (int j = 0; j < JJ; ++j) { Lg[j] = __expf(Lg[j] - mx); sum += Lg[j]; }
        const float inv = 1.f / sum;
#pragma unroll
        for (int j = 0; j < JJ; ++j) acc[j] += (Lg[j] * inv) * U[j];
    }
#pragma unroll
    for (int j = 0; j < JJ; ++j)
        atomicAdd(&s_acc[(b * JJ + j) * DD + d], acc[j]);
}

extern "C" void kernel_launch(void* const* d_in, const int* in_sizes, int n_in,
                              void* d_out, int out_size, void* d_ws, size_t ws_size,
                              hipStream_t stream) {
    const float* x = (const float*)d_in[0];   // [B, I, K]
    const float* W = (const float*)d_in[1];   // [J, I, D, K]
    float* out = (float*)d_out;               // [B, J, D]

    unsigned* bar = (unsigned*)d_ws;                       // 16 u32 (64B)
    float* vT     = (float*)((char*)d_ws + 64);            // 40960 f32, layout [j][d][b]
    _Float16* p   = (_Float16*)(vT + BB * JJ * DD);        // 16*128*2560 f16
    short* xTb    = (short*)(p + (size_t)16 * 128 * 2560); // I*B*K bf16
    short* Wb     = xTb + (size_t)II * BB * KK;            // J*I*D*K bf16
    const size_t need = 64 + (size_t)(BB * JJ * DD) * 4
                      + (size_t)16 * 128 * 2560 * 2
                      + ((size_t)II * BB * KK + (size_t)JJ * II * DD * KK) * 2;

    if (ws_size >= need) {
        hipMemsetAsync(bar, 0, 64, stream);
        pre_kernel<<<1280 + 2048, 256, 0, stream>>>(x, W, xTb, Wb);

        dim3 rg(128, 4);
        // round 1: uniform c (1/J folded into squash scale), tail-rs MODE0
        round_mfma<0, 0><<<rg, 256, 0, stream>>>(xTb, Wb, vT, p, out, bar);
        // round 2: logits = v1 . U, tail-rs MODE1
        round_mfma<1, 1><<<rg, 256, 0, stream>>>(xTb, Wb, vT, p, out, bar);
        // round 3: logits = (v1+v2) . U, tail-rs MODE2 -> out
        round_mfma<1, 2><<<rg, 256, 0, stream>>>(xTb, Wb, vT, p, out, bar);
    } else {
        // fallback: round-1 passing path
        float* s_acc = (float*)d_ws;
        float* v_buf = s_acc + BB * JJ * DD;
        const int NS = BB * JJ * DD;
        dim3 rg(II / IT_OLD, BB / BT_OLD);
        zero_kernel<<<(NS + 255) / 256, 256, 0, stream>>>(s_acc, NS);
        round1_old<<<rg, 256, 0, stream>>>(x, W, s_acc);
        squash_old<<<(BB * JJ + 255) / 256, 256, 0, stream>>>(s_acc, v_buf, 0.1f, 0, 1);
        round_old<<<rg, 256, 0, stream>>>(x, W, v_buf, s_acc);
        squash_old<<<(BB * JJ + 255) / 256, 256, 0, stream>>>(s_acc, v_buf, 1.0f, 1, 1);
        round_old<<<rg, 256, 0, stream>>>(x, W, v_buf, s_acc);
        squash_old<<<(BB * JJ + 255) / 256, 256, 0, stream>>>(s_acc, out, 1.0f, 0, 0);
    }
}

// Round 9
// 140.281 us; speedup vs baseline: 1.9110x; 1.9110x over previous
//
#include <hip/hip_runtime.h>
#include <math.h>

// CapsuleLayer dynamic routing, fp32 in/out. B=256, I=2048, K=8, J=10, D=16.
// R13: R6 champion structure (139.9us: 7 kernels, 128 chunks, 512 blocks,
// 2 LDS buffers, 8B p stores, vT [j][d][b]) with round staging rewritten to
// global_load_lds width=16 (async DMA global->LDS): removes 14 reg loads +
// 14 ds_writes + ~56 staging VGPRs per thread and ONE barrier (one
// __syncthreads drains vmcnt(0) for both buffers; R6's reg-prefetch overlap
// was nil since both sub-chunks were issued together anyway).
// R9/R10/R12 verdict: ALL in-kernel cross-block sync forms cost 40-100us on
// this 8-XCD part -> multi-kernel boundaries (~10us) are the cheaper sync.
// Round core math unchanged (mfma_f32_16x16x32_bf16, C/D col=lane&15=b,
// row=(lane>>4)*4+reg=d; round 1 packs 4 i's into K=32).
//
// ws: vT f32[40960] | p f16[16*128*2560] | xTb bf16[I*B*K] | Wb bf16[J*I*D*K] (~24.3 MB)

#define BB 256
#define II 2048
#define KK 8
#define JJ 10
#define DD 16

typedef __attribute__((ext_vector_type(4))) float f32x4;
typedef __attribute__((ext_vector_type(8))) short short8;

__device__ __forceinline__ short f2bf(float f) {
    union { float f; unsigned u; } v; v.f = f;
    unsigned r = v.u + 0x7FFFu + ((v.u >> 16) & 1u);   // RNE
    return (short)(r >> 16);
}

// async 16B/lane global->LDS: wave-uniform LDS base, lane offset = lane*16B (HW)
__device__ __forceinline__ void gload16(const short* g, short* l) {
    __builtin_amdgcn_global_load_lds(
        (const __attribute__((address_space(1))) unsigned int*)g,
        (__attribute__((address_space(3))) unsigned int*)l,
        16, 0, 0);
}

// Fused preprocessing:
//   blocks [0,1280): W fp32 [j,i,d,k] -> Wb bf16 same layout (k contiguous).
//   blocks [1280,3328): x fp32 [b,i,k] -> xTb bf16 [i,b,k], LDS transpose tile.
__global__ __launch_bounds__(256) void pre_kernel(const float* __restrict__ x,
                                                  const float* __restrict__ W,
                                                  short* __restrict__ xTb,
                                                  short* __restrict__ Wb) {
    __shared__ float4 tile[8 * 66];
    const int t = threadIdx.x;
    const int bid = blockIdx.x;
    if (bid < 1280) {
        const int idx = bid * 256 + t;
        const float4* src = (const float4*)(W + (size_t)idx * 8);
        const float4 a = src[0], b = src[1];
        short8 o;
        o[0] = f2bf(a.x); o[1] = f2bf(a.y); o[2] = f2bf(a.z); o[3] = f2bf(a.w);
        o[4] = f2bf(b.x); o[5] = f2bf(b.y); o[6] = f2bf(b.z); o[7] = f2bf(b.w);
        *(short8*)(Wb + (size_t)idx * 8) = o;
    } else {
        const int bb = bid - 1280;
        const int b0 = (bb >> 8) * 32, i0 = (bb & 255) * 8;
        {
            const int lb = t >> 3, li = t & 7;
            const float4* src = (const float4*)(x + ((b0 + lb) * II + (i0 + li)) * KK);
            tile[li * 66 + lb * 2 + 0] = src[0];
            tile[li * 66 + lb * 2 + 1] = src[1];
        }
        __syncthreads();
        {
            const int ri = t >> 5, rb = t & 31;
            const float4 p0 = tile[ri * 66 + rb * 2 + 0];
            const float4 p1 = tile[ri * 66 + rb * 2 + 1];
            short8 o;
            o[0] = f2bf(p0.x); o[1] = f2bf(p0.y); o[2] = f2bf(p0.z); o[3] = f2bf(p0.w);
            o[4] = f2bf(p1.x); o[5] = f2bf(p1.y); o[6] = f2bf(p1.z); o[7] = f2bf(p1.w);
            *(short8*)(xTb + ((size_t)(i0 + ri) * BB + (b0 + rb)) * KK) = o;
        }
    }
}

// ---- staging helpers: 28 segments of 1024B per 8-i sub-chunk (20 W halves + 8 x rows) ----
// LDS layout per buffer (shorts): Wl[j][il][d][k] at j*1024+il*128+d*8 ; Xl at 10240+il*512+b*8
#define LBUF 14336   // shorts per buffer

__device__ __forceinline__ void seg_src_dst(int s, int i0, int b0,
                                            const short* __restrict__ xTb,
                                            const short* __restrict__ Wb,
                                            const short** src, int* dst) {
    if (s < 20) {
        const int j = s >> 1, h = s & 1;
        *src = Wb + ((size_t)(j * II + i0) * DD) * KK + h * 512;
        *dst = j * 1024 + h * 512;
    } else {
        const int il = s - 20;
        *src = xTb + ((size_t)(i0 + il) * BB + b0) * KK;
        *dst = 10240 + il * 512;
    }
}

// One routing round. grid (128, 4), block 256 (4 waves = 4 b-tiles), 16 i per
// block. Staging: 28 segments async-DMA'd to L[0]/L[1] via global_load_lds
// (width 16, wave-uniform LDS base + lane*16B); ONE __syncthreads (drains
// vmcnt(0) for all 14 per-thread DMAs) then both sub-chunks computed
// back-to-back with no further barriers.
// Partials p[bt][chunk=blockIdx.x][j*64 + lane] (4 fp16 per lane, 8B store).
template <int USE_C>
__global__ __launch_bounds__(256) void round_mfma(
    const short* __restrict__ xTb, const short* __restrict__ Wb,
    const float* __restrict__ vT, _Float16* __restrict__ p)
{
    __shared__ short L[2][LBUF];
    const int t = threadIdx.x;
    const int lane = t & 63, wv = t >> 6;
    const int col = lane & 15, q = lane >> 4;
    const int b0 = blockIdx.y * 64;
    const int bl = wv * 16 + col;          // b within block for this wave's tile
    const int i0 = blockIdx.x * 16;

    // ---- async-stage both sub-chunks (4 waves interleave the 28 segments) ----
#pragma unroll
    for (int n = 0; n < 7; ++n) {
        const int s = wv + n * 4;
        const short* src; int dst;
        seg_src_dst(s, i0, b0, xTb, Wb, &src, &dst);
        gload16(src + lane * 8, &L[0][dst]);
        seg_src_dst(s, i0 + 8, b0, xTb, Wb, &src, &dst);
        gload16(src + lane * 8, &L[1][dst]);
    }

    float vfrag[JJ][4];
    if (USE_C) {   // overlaps with the DMA in flight
#pragma unroll
        for (int j = 0; j < JJ; ++j)
#pragma unroll
            for (int r = 0; r < 4; ++r)
                vfrag[j][r] = vT[(j * DD + q * 4 + r) * BB + b0 + bl];
    }

    __syncthreads();   // drains vmcnt(0): all 28 segments landed in L[0]/L[1]

    f32x4 sfrag[JJ];
#pragma unroll
    for (int j = 0; j < JJ; ++j) sfrag[j] = (f32x4){0.f, 0.f, 0.f, 0.f};

#pragma unroll
    for (int sc = 0; sc < 2; ++sc) {
        const short* Lb = L[sc];
        if (USE_C) {
            for (int il = 0; il < 8; ++il) {
                short8 A[JJ], Bf;
                const short8 z = (short8){0, 0, 0, 0, 0, 0, 0, 0};
                Bf = z;
#pragma unroll
                for (int j = 0; j < JJ; ++j) A[j] = z;
                if (q == 0) {   // kc 0..7 real, quads 1..3 stay zero (k-pad 8->32)
                    Bf = *(const short8*)(&Lb[10240 + il * 512 + bl * 8]);
#pragma unroll
                    for (int j = 0; j < JJ; ++j)
                        A[j] = *(const short8*)(&Lb[j * 1024 + il * 128 + col * 8]);
                }
                f32x4 U[JJ];
#pragma unroll
                for (int j = 0; j < JJ; ++j)
                    U[j] = __builtin_amdgcn_mfma_f32_16x16x32_bf16(
                        A[j], Bf, (f32x4){0.f, 0.f, 0.f, 0.f}, 0, 0, 0);
                float Lg[JJ];
#pragma unroll
                for (int j = 0; j < JJ; ++j)
                    Lg[j] = vfrag[j][0] * U[j][0] + vfrag[j][1] * U[j][1]
                          + vfrag[j][2] * U[j][2] + vfrag[j][3] * U[j][3];
#pragma unroll
                for (int j = 0; j < JJ; ++j) {   // reduce over the 4 d-quads
                    Lg[j] += __shfl_xor(Lg[j], 16, 64);
                    Lg[j] += __shfl_xor(Lg[j], 32, 64);
                }
                float sum = 0.f;   // |logit| is O(1): no max-subtraction needed
#pragma unroll
                for (int j = 0; j < JJ; ++j) { Lg[j] = __expf(Lg[j]); sum += Lg[j]; }
                const float inv = __builtin_amdgcn_rcpf(sum);
#pragma unroll
                for (int j = 0; j < JJ; ++j) {
                    const float c = Lg[j] * inv;
#pragma unroll
                    for (int r = 0; r < 4; ++r) sfrag[j][r] += c * U[j][r];
                }
            }
        } else {
            // round 1: sum_i U. Pack 4 i's per MFMA: kc = q*8 + k -> i_local = q.
#pragma unroll
            for (int s = 0; s < 2; ++s) {
                const int il = s * 4 + q;
                const short8 Bf = *(const short8*)(&Lb[10240 + il * 512 + bl * 8]);
#pragma unroll
                for (int j = 0; j < JJ; ++j) {
                    const short8 A = *(const short8*)(&Lb[j * 1024 + il * 128 + col * 8]);
                    sfrag[j] = __builtin_amdgcn_mfma_f32_16x16x32_bf16(A, Bf, sfrag[j], 0, 0, 0);
                }
            }
        }
    }

    // epilogue: wave-private partial chunk, 10 coalesced 8B stores
    _Float16* pp = p + ((size_t)(blockIdx.y * 4 + wv) * 128 + blockIdx.x) * (JJ * 256);
#pragma unroll
    for (int j = 0; j < JJ; ++j) {
        union { uint2 u; _Float16 h[4]; } pk;
        pk.h[0] = (_Float16)sfrag[j][0];
        pk.h[1] = (_Float16)sfrag[j][1];
        pk.h[2] = (_Float16)sfrag[j][2];
        pk.h[3] = (_Float16)sfrag[j][3];
        *(uint2*)(pp + (size_t)(j * 64 + lane) * 4) = pk.u;
    }
}

// Fused reduce + squash. grid (10 j, 16 bt), block 256 = 64 elem-groups x 4
// chunk-groups. Thread (eg,cg) sums 32 chunks of an 8B (4 fp16) slot ->
// LDS combine 4 cgs -> t<64 squashes in-register (shfl over d-quads).
// MODE 0: vT = squash(scale*s)   MODE 1: vT += squash(s)   MODE 2: out = squash(s)
template <int MODE>
__global__ __launch_bounds__(256) void rs_kernel(const _Float16* __restrict__ p,
                                                 float* __restrict__ vT,
                                                 float* __restrict__ out, float scale) {
    __shared__ f32x4 red[256];
    const int t = threadIdx.x;
    const int j = blockIdx.x, bt = blockIdx.y;
    const int eg = t & 63, cg = t >> 6;

    const _Float16* pp = p + ((size_t)bt * 128 + cg * 32) * (JJ * 256) + j * 256 + eg * 4;
    float s0 = 0.f, s1 = 0.f, s2 = 0.f, s3 = 0.f;
#pragma unroll 8
    for (int ch = 0; ch < 32; ++ch) {
        union { uint2 u; _Float16 h[4]; } cv;
        cv.u = *(const uint2*)(pp + (size_t)ch * (JJ * 256));
        s0 += (float)cv.h[0]; s1 += (float)cv.h[1];
        s2 += (float)cv.h[2]; s3 += (float)cv.h[3];
    }
    red[t] = (f32x4){s0, s1, s2, s3};
    __syncthreads();
    if (t < 64) {
        f32x4 a = red[t];
        a += red[64 + t]; a += red[128 + t]; a += red[192 + t];
        const float x0 = a[0] * scale, x1 = a[1] * scale;
        const float x2 = a[2] * scale, x3 = a[3] * scale;
        float ss = x0 * x0 + x1 * x1 + x2 * x2 + x3 * x3;
        ss += __shfl_xor(ss, 16, 64);       // sum over the 4 d-quads (same bc)
        ss += __shfl_xor(ss, 32, 64);
        const float coef = ss / (1.f + ss) / sqrtf(ss + 1e-7f);
        const int qd = t >> 4, bc = t & 15;
        const float v[4] = {coef * x0, coef * x1, coef * x2, coef * x3};
#pragma unroll
        for (int r = 0; r < 4; ++r) {
            const int d = qd * 4 + r;
            if (MODE == 0) vT[(j * DD + d) * BB + bt * 16 + bc] = v[r];
            if (MODE == 1) vT[(j * DD + d) * BB + bt * 16 + bc] += v[r];
            if (MODE == 2) out[((bt * 16 + bc) * JJ + j) * DD + d] = v[r];
        }
    }
}

// ---------------- fallback path (round-1 passing kernel, 365us) ----------------
#define IT_OLD 32
#define BT_OLD 16

__global__ __launch_bounds__(256) void zero_kernel(float* __restrict__ p, int n) {
    int idx = blockIdx.x * blockDim.x + threadIdx.x;
    if (idx < n) p[idx] = 0.f;
}

__global__ __launch_bounds__(256) void squash_old(float* __restrict__ s_acc,
                                                  float* __restrict__ dst, float scale,
                                                  int add_to_dst, int zero_src) {
    int idx = blockIdx.x * blockDim.x + threadIdx.x;
    if (idx >= BB * JJ) return;
    float s[DD];
    float ss = 0.f;
#pragma unroll
    for (int d = 0; d < DD; ++d) {
        s[d] = s_acc[idx * DD + d] * scale;
        ss += s[d] * s[d];
    }
    const float coef = ss / (1.f + ss) / sqrtf(ss + 1e-7f);
#pragma unroll
    for (int d = 0; d < DD; ++d) {
        const float vv = coef * s[d];
        if (add_to_dst) dst[idx * DD + d] += vv;
        else            dst[idx * DD + d] = vv;
        if (zero_src)   s_acc[idx * DD + d] = 0.f;
    }
}

__global__ __launch_bounds__(256) void round1_old(const float* __restrict__ x,
                                                  const float* __restrict__ W,
                                                  float* __restrict__ s_acc) {
    const int t = threadIdx.x;
    const int d = t & 15;
    const int bq = t >> 4;
    const int b = blockIdx.y * BT_OLD + bq;
    const int i0 = blockIdx.x * IT_OLD;
    float acc[JJ];
#pragma unroll
    for (int j = 0; j < JJ; ++j) acc[j] = 0.f;
    for (int ii = 0; ii < IT_OLD; ++ii) {
        const int i = i0 + ii;
        const float* xp = x + ((b * II) + i) * KK;
        const float4 xa = *(const float4*)(xp);
        const float4 xb = *(const float4*)(xp + 4);
#pragma unroll
        for (int j = 0; j < JJ; ++j) {
            const float* wp = W + (((j * II + i) * DD + d) * KK);
            const float4 w0 = *(const float4*)(wp);
            const float4 w1 = *(const float4*)(wp + 4);
            acc[j] += w0.x*xa.x + w0.y*xa.y + w0.z*xa.z + w0.w*xa.w
                    + w1.x*xb.x + w1.y*xb.y + w1.z*xb.z + w1.w*xb.w;
        }
    }
#pragma unroll
    for (int j = 0; j < JJ; ++j)
        atomicAdd(&s_acc[(b * JJ + j) * DD + d], acc[j]);
}

__global__ __launch_bounds__(256) void round_old(const float* __restrict__ x,
                                                 const float* __restrict__ W,
                                                 const float* __restrict__ v,
                                                 float* __restrict__ s_acc) {
    const int t = threadIdx.x;
    const int d = t & 15;
    const int bq = t >> 4;
    const int b = blockIdx.y * BT_OLD + bq;
    const int i0 = blockIdx.x * IT_OLD;
    float vr[JJ], acc[JJ];
#pragma unroll
    for (int j = 0; j < JJ; ++j) {
        vr[j] = v[(b * JJ + j) * DD + d];
        acc[j] = 0.f;
    }
    for (int ii = 0; ii < IT_OLD; ++ii) {
        const int i = i0 + ii;
        const float* xp = x + ((b * II) + i) * KK;
        const float4 xa = *(const float4*)(xp);
        const float4 xb = *(const float4*)(xp + 4);
        float U[JJ], Lg[JJ];
#pragma unroll
        for (int j = 0; j < JJ; ++j) {
            const float* wp = W + (((j * II + i) * DD + d) * KK);
            const float4 w0 = *(const float4*)(wp);
            const float4 w1 = *(const float4*)(wp + 4);
            U[j] = w0.x*xa.x + w0.y*xa.y + w0.z*xa.z + w0.w*xa.w
                 + w1.x*xb.x + w1.y*xb.y + w1.z*xb.z + w1.w*xb.w;
            Lg[j] = vr[j] * U[j];
        }
#pragma unroll
        for (int m = 8; m >= 1; m >>= 1) {
#pragma unroll
            for (int j = 0; j < JJ; ++j) Lg[j] += __shfl_xor(Lg[j], m, 64);
        }
        float mx = Lg[0];
#pragma unroll
        for (int j = 1; j < JJ; ++j) mx = fmaxf(mx, Lg[j]);
        float sum = 0.f;
#pragma unroll
        for (int j = 0; j < JJ; ++j) { Lg[j] = __expf(Lg[j] - mx); sum += Lg[j]; }
        const float inv = 1.f / sum;
#pragma unroll
        for (int j = 0; j < JJ; ++j) acc[j] += (Lg[j] * inv) * U[j];
    }
#pragma unroll
    for (int j = 0; j < JJ; ++j)
        atomicAdd(&s_acc[(b * JJ + j) * DD + d], acc[j]);
}

extern "C" void kernel_launch(void* const* d_in, const int* in_sizes, int n_in,
                              void* d_out, int out_size, void* d_ws, size_t ws_size,
                              hipStream_t stream) {
    const float* x = (const float*)d_in[0];   // [B, I, K]
    const float* W = (const float*)d_in[1];   // [J, I, D, K]
    float* out = (float*)d_out;               // [B, J, D]

    float* vT     = (float*)d_ws;                          // 40960 f32, layout [j][d][b]
    _Float16* p   = (_Float16*)(vT + BB * JJ * DD);        // 16*128*2560 f16
    short* xTb    = (short*)(p + (size_t)16 * 128 * 2560); // I*B*K bf16
    short* Wb     = xTb + (size_t)II * BB * KK;            // J*I*D*K bf16
    const size_t need = (size_t)(BB * JJ * DD) * 4
                      + (size_t)16 * 128 * 2560 * 2
                      + ((size_t)II * BB * KK + (size_t)JJ * II * DD * KK) * 2;

    if (ws_size >= need) {
        pre_kernel<<<1280 + 2048, 256, 0, stream>>>(x, W, xTb, Wb);

        dim3 rg(128, 4);
        dim3 sg(JJ, 16);
        // round 1: uniform c (1/J folded into squash scale)
        round_mfma<0><<<rg, 256, 0, stream>>>(xTb, Wb, vT, p);
        rs_kernel<0><<<sg, 256, 0, stream>>>(p, vT, out, 0.1f);
        // round 2: logits = v1 . U
        round_mfma<1><<<rg, 256, 0, stream>>>(xTb, Wb, vT, p);
        rs_kernel<1><<<sg, 256, 0, stream>>>(p, vT, out, 1.0f);
        // round 3: logits = (v1+v2) . U
        round_mfma<1><<<rg, 256, 0, stream>>>(xTb, Wb, vT, p);
        rs_kernel<2><<<sg, 256, 0, stream>>>(p, vT, out, 1.0f);
    } else {
        // fallback: round-1 passing path
        float* s_acc = (float*)d_ws;
        float* v_buf = s_acc + BB * JJ * DD;
        const int NS = BB * JJ * DD;
        dim3 rg(II / IT_OLD, BB / BT_OLD);
        zero_kernel<<<(NS + 255) / 256, 256, 0, stream>>>(s_acc, NS);
        round1_old<<<rg, 256, 0, stream>>>(x, W, s_acc);
        squash_old<<<(BB * JJ + 255) / 256, 256, 0, stream>>>(s_acc, v_buf, 0.1f, 0, 1);
        round_old<<<rg, 256, 0, stream>>>(x, W, v_buf, s_acc);
        squash_old<<<(BB * JJ + 255) / 256, 256, 0, stream>>>(s_acc, v_buf, 1.0f, 1, 1);
        round_old<<<rg, 256, 0, stream>>>(x, W, v_buf, s_acc);
        squash_old<<<(BB * JJ + 255) / 256, 256, 0, stream>>>(s_acc, out, 1.0f, 0, 0);
    }
}

// Round 10
// 136.611 us; speedup vs baseline: 1.9624x; 1.0269x over previous
//
#include <hip/hip_runtime.h>
#include <math.h>

// CapsuleLayer dynamic routing, fp32 in/out. B=256, I=2048, K=8, J=10, D=16.
// R14: R13 champion (140.3us: 7 kernels, global_load_lds staging, 128 chunks,
// 512 blocks, 8B p stores) + dependent-chain ILP:
//  (1) round il-loop unroll 2 -> two independent softmax chains in flight
//      (R13 lesson: staging cost is nil; R9 counters: rounds latency-bound,
//      VALUBusy 5.5% MfmaUtil 1% -> serial MFMA->dot->shfl->exp->rcp chains).
//  (2) rs 512 threads: 8 chunk-groups x 16 serial loads (was 4x32) -- halves
//      serial load depth, 2x waves/CU on the 160 rs blocks.
// R9/R10/R12 verdict stands: all in-kernel cross-block sync costs 40-100us on
// this 8-XCD part; 7-kernel chain with ~10us boundaries is the cheaper sync.
// Round core math unchanged (mfma_f32_16x16x32_bf16, C/D col=lane&15=b,
// row=(lane>>4)*4+reg=d; round 1 packs 4 i's into K=32).
//
// ws: vT f32[40960] | p f16[16*128*2560] | xTb bf16[I*B*K] | Wb bf16[J*I*D*K] (~24.3 MB)

#define BB 256
#define II 2048
#define KK 8
#define JJ 10
#define DD 16

typedef __attribute__((ext_vector_type(4))) float f32x4;
typedef __attribute__((ext_vector_type(8))) short short8;

__device__ __forceinline__ short f2bf(float f) {
    union { float f; unsigned u; } v; v.f = f;
    unsigned r = v.u + 0x7FFFu + ((v.u >> 16) & 1u);   // RNE
    return (short)(r >> 16);
}

// async 16B/lane global->LDS: wave-uniform LDS base, lane offset = lane*16B (HW)
__device__ __forceinline__ void gload16(const short* g, short* l) {
    __builtin_amdgcn_global_load_lds(
        (const __attribute__((address_space(1))) unsigned int*)g,
        (__attribute__((address_space(3))) unsigned int*)l,
        16, 0, 0);
}

// Fused preprocessing:
//   blocks [0,1280): W fp32 [j,i,d,k] -> Wb bf16 same layout (k contiguous).
//   blocks [1280,3328): x fp32 [b,i,k] -> xTb bf16 [i,b,k], LDS transpose tile.
__global__ __launch_bounds__(256) void pre_kernel(const float* __restrict__ x,
                                                  const float* __restrict__ W,
                                                  short* __restrict__ xTb,
                                                  short* __restrict__ Wb) {
    __shared__ float4 tile[8 * 66];
    const int t = threadIdx.x;
    const int bid = blockIdx.x;
    if (bid < 1280) {
        const int idx = bid * 256 + t;
        const float4* src = (const float4*)(W + (size_t)idx * 8);
        const float4 a = src[0], b = src[1];
        short8 o;
        o[0] = f2bf(a.x); o[1] = f2bf(a.y); o[2] = f2bf(a.z); o[3] = f2bf(a.w);
        o[4] = f2bf(b.x); o[5] = f2bf(b.y); o[6] = f2bf(b.z); o[7] = f2bf(b.w);
        *(short8*)(Wb + (size_t)idx * 8) = o;
    } else {
        const int bb = bid - 1280;
        const int b0 = (bb >> 8) * 32, i0 = (bb & 255) * 8;
        {
            const int lb = t >> 3, li = t & 7;
            const float4* src = (const float4*)(x + ((b0 + lb) * II + (i0 + li)) * KK);
            tile[li * 66 + lb * 2 + 0] = src[0];
            tile[li * 66 + lb * 2 + 1] = src[1];
        }
        __syncthreads();
        {
            const int ri = t >> 5, rb = t & 31;
            const float4 p0 = tile[ri * 66 + rb * 2 + 0];
            const float4 p1 = tile[ri * 66 + rb * 2 + 1];
            short8 o;
            o[0] = f2bf(p0.x); o[1] = f2bf(p0.y); o[2] = f2bf(p0.z); o[3] = f2bf(p0.w);
            o[4] = f2bf(p1.x); o[5] = f2bf(p1.y); o[6] = f2bf(p1.z); o[7] = f2bf(p1.w);
            *(short8*)(xTb + ((size_t)(i0 + ri) * BB + (b0 + rb)) * KK) = o;
        }
    }
}

// ---- staging helpers: 28 segments of 1024B per 8-i sub-chunk (20 W halves + 8 x rows) ----
// LDS layout per buffer (shorts): Wl[j][il][d][k] at j*1024+il*128+d*8 ; Xl at 10240+il*512+b*8
#define LBUF 14336   // shorts per buffer

__device__ __forceinline__ void seg_src_dst(int s, int i0, int b0,
                                            const short* __restrict__ xTb,
                                            const short* __restrict__ Wb,
                                            const short** src, int* dst) {
    if (s < 20) {
        const int j = s >> 1, h = s & 1;
        *src = Wb + ((size_t)(j * II + i0) * DD) * KK + h * 512;
        *dst = j * 1024 + h * 512;
    } else {
        const int il = s - 20;
        *src = xTb + ((size_t)(i0 + il) * BB + b0) * KK;
        *dst = 10240 + il * 512;
    }
}

// One routing round. grid (128, 4), block 256 (4 waves = 4 b-tiles), 16 i per
// block. Staging: 28 segments async-DMA'd to L[0]/L[1] via global_load_lds
// (width 16); one __syncthreads drains vmcnt(0), then both sub-chunks computed
// back-to-back. il loop unrolled x2 for dual softmax chains in flight.
// Partials p[bt][chunk=blockIdx.x][j*64 + lane] (4 fp16 per lane, 8B store).
template <int USE_C>
__global__ __launch_bounds__(256) void round_mfma(
    const short* __restrict__ xTb, const short* __restrict__ Wb,
    const float* __restrict__ vT, _Float16* __restrict__ p)
{
    __shared__ short L[2][LBUF];
    const int t = threadIdx.x;
    const int lane = t & 63, wv = t >> 6;
    const int col = lane & 15, q = lane >> 4;
    const int b0 = blockIdx.y * 64;
    const int bl = wv * 16 + col;          // b within block for this wave's tile
    const int i0 = blockIdx.x * 16;

    // ---- async-stage both sub-chunks (4 waves interleave the 28 segments) ----
#pragma unroll
    for (int n = 0; n < 7; ++n) {
        const int s = wv + n * 4;
        const short* src; int dst;
        seg_src_dst(s, i0, b0, xTb, Wb, &src, &dst);
        gload16(src + lane * 8, &L[0][dst]);
        seg_src_dst(s, i0 + 8, b0, xTb, Wb, &src, &dst);
        gload16(src + lane * 8, &L[1][dst]);
    }

    float vfrag[JJ][4];
    if (USE_C) {   // overlaps with the DMA in flight
#pragma unroll
        for (int j = 0; j < JJ; ++j)
#pragma unroll
            for (int r = 0; r < 4; ++r)
                vfrag[j][r] = vT[(j * DD + q * 4 + r) * BB + b0 + bl];
    }

    __syncthreads();   // drains vmcnt(0): all 28 segments landed in L[0]/L[1]

    f32x4 sfrag[JJ];
#pragma unroll
    for (int j = 0; j < JJ; ++j) sfrag[j] = (f32x4){0.f, 0.f, 0.f, 0.f};

#pragma unroll
    for (int sc = 0; sc < 2; ++sc) {
        const short* Lb = L[sc];
        if (USE_C) {
#pragma unroll 2
            for (int il = 0; il < 8; ++il) {
                short8 A[JJ], Bf;
                const short8 z = (short8){0, 0, 0, 0, 0, 0, 0, 0};
                Bf = z;
#pragma unroll
                for (int j = 0; j < JJ; ++j) A[j] = z;
                if (q == 0) {   // kc 0..7 real, quads 1..3 stay zero (k-pad 8->32)
                    Bf = *(const short8*)(&Lb[10240 + il * 512 + bl * 8]);
#pragma unroll
                    for (int j = 0; j < JJ; ++j)
                        A[j] = *(const short8*)(&Lb[j * 1024 + il * 128 + col * 8]);
                }
                f32x4 U[JJ];
#pragma unroll
                for (int j = 0; j < JJ; ++j)
                    U[j] = __builtin_amdgcn_mfma_f32_16x16x32_bf16(
                        A[j], Bf, (f32x4){0.f, 0.f, 0.f, 0.f}, 0, 0, 0);
                float Lg[JJ];
#pragma unroll
                for (int j = 0; j < JJ; ++j)
                    Lg[j] = vfrag[j][0] * U[j][0] + vfrag[j][1] * U[j][1]
                          + vfrag[j][2] * U[j][2] + vfrag[j][3] * U[j][3];
#pragma unroll
                for (int j = 0; j < JJ; ++j) {   // reduce over the 4 d-quads
                    Lg[j] += __shfl_xor(Lg[j], 16, 64);
                    Lg[j] += __shfl_xor(Lg[j], 32, 64);
                }
                float sum = 0.f;   // |logit| is O(1): no max-subtraction needed
#pragma unroll
                for (int j = 0; j < JJ; ++j) { Lg[j] = __expf(Lg[j]); sum += Lg[j]; }
                const float inv = __builtin_amdgcn_rcpf(sum);
#pragma unroll
                for (int j = 0; j < JJ; ++j) {
                    const float c = Lg[j] * inv;
#pragma unroll
                    for (int r = 0; r < 4; ++r) sfrag[j][r] += c * U[j][r];
                }
            }
        } else {
            // round 1: sum_i U. Pack 4 i's per MFMA: kc = q*8 + k -> i_local = q.
#pragma unroll
            for (int s = 0; s < 2; ++s) {
                const int il = s * 4 + q;
                const short8 Bf = *(const short8*)(&Lb[10240 + il * 512 + bl * 8]);
#pragma unroll
                for (int j = 0; j < JJ; ++j) {
                    const short8 A = *(const short8*)(&Lb[j * 1024 + il * 128 + col * 8]);
                    sfrag[j] = __builtin_amdgcn_mfma_f32_16x16x32_bf16(A, Bf, sfrag[j], 0, 0, 0);
                }
            }
        }
    }

    // epilogue: wave-private partial chunk, 10 coalesced 8B stores
    _Float16* pp = p + ((size_t)(blockIdx.y * 4 + wv) * 128 + blockIdx.x) * (JJ * 256);
#pragma unroll
    for (int j = 0; j < JJ; ++j) {
        union { uint2 u; _Float16 h[4]; } pk;
        pk.h[0] = (_Float16)sfrag[j][0];
        pk.h[1] = (_Float16)sfrag[j][1];
        pk.h[2] = (_Float16)sfrag[j][2];
        pk.h[3] = (_Float16)sfrag[j][3];
        *(uint2*)(pp + (size_t)(j * 64 + lane) * 4) = pk.u;
    }
}

// Fused reduce + squash. grid (10 j, 16 bt), block 512 = 64 elem-groups x 8
// chunk-groups. Thread (eg,cg) sums 16 chunks of an 8B (4 fp16) slot ->
// LDS combine 8 cgs -> t<64 squashes in-register (shfl over d-quads).
// MODE 0: vT = squash(scale*s)   MODE 1: vT += squash(s)   MODE 2: out = squash(s)
template <int MODE>
__global__ __launch_bounds__(512) void rs_kernel(const _Float16* __restrict__ p,
                                                 float* __restrict__ vT,
                                                 float* __restrict__ out, float scale) {
    __shared__ f32x4 red[512];
    const int t = threadIdx.x;
    const int j = blockIdx.x, bt = blockIdx.y;
    const int eg = t & 63, cg = t >> 6;

    const _Float16* pp = p + ((size_t)bt * 128 + cg * 16) * (JJ * 256) + j * 256 + eg * 4;
    float s0 = 0.f, s1 = 0.f, s2 = 0.f, s3 = 0.f;
#pragma unroll 8
    for (int ch = 0; ch < 16; ++ch) {
        union { uint2 u; _Float16 h[4]; } cv;
        cv.u = *(const uint2*)(pp + (size_t)ch * (JJ * 256));
        s0 += (float)cv.h[0]; s1 += (float)cv.h[1];
        s2 += (float)cv.h[2]; s3 += (float)cv.h[3];
    }
    red[t] = (f32x4){s0, s1, s2, s3};
    __syncthreads();
    if (t < 64) {
        f32x4 a = red[t];
#pragma unroll
        for (int g = 1; g < 8; ++g) a += red[64 * g + t];
        const float x0 = a[0] * scale, x1 = a[1] * scale;
        const float x2 = a[2] * scale, x3 = a[3] * scale;
        float ss = x0 * x0 + x1 * x1 + x2 * x2 + x3 * x3;
        ss += __shfl_xor(ss, 16, 64);       // sum over the 4 d-quads (same bc)
        ss += __shfl_xor(ss, 32, 64);
        const float coef = ss / (1.f + ss) / sqrtf(ss + 1e-7f);
        const int qd = t >> 4, bc = t & 15;
        const float v[4] = {coef * x0, coef * x1, coef * x2, coef * x3};
#pragma unroll
        for (int r = 0; r < 4; ++r) {
            const int d = qd * 4 + r;
            if (MODE == 0) vT[(j * DD + d) * BB + bt * 16 + bc] = v[r];
            if (MODE == 1) vT[(j * DD + d) * BB + bt * 16 + bc] += v[r];
            if (MODE == 2) out[((bt * 16 + bc) * JJ + j) * DD + d] = v[r];
        }
    }
}

// ---------------- fallback path (round-1 passing kernel, 365us) ----------------
#define IT_OLD 32
#define BT_OLD 16

__global__ __launch_bounds__(256) void zero_kernel(float* __restrict__ p, int n) {
    int idx = blockIdx.x * blockDim.x + threadIdx.x;
    if (idx < n) p[idx] = 0.f;
}

__global__ __launch_bounds__(256) void squash_old(float* __restrict__ s_acc,
                                                  float* __restrict__ dst, float scale,
                                                  int add_to_dst, int zero_src) {
    int idx = blockIdx.x * blockDim.x + threadIdx.x;
    if (idx >= BB * JJ) return;
    float s[DD];
    float ss = 0.f;
#pragma unroll
    for (int d = 0; d < DD; ++d) {
        s[d] = s_acc[idx * DD + d] * scale;
        ss += s[d] * s[d];
    }
    const float coef = ss / (1.f + ss) / sqrtf(ss + 1e-7f);
#pragma unroll
    for (int d = 0; d < DD; ++d) {
        const float vv = coef * s[d];
        if (add_to_dst) dst[idx * DD + d] += vv;
        else            dst[idx * DD + d] = vv;
        if (zero_src)   s_acc[idx * DD + d] = 0.f;
    }
}

__global__ __launch_bounds__(256) void round1_old(const float* __restrict__ x,
                                                  const float* __restrict__ W,
                                                  float* __restrict__ s_acc) {
    const int t = threadIdx.x;
    const int d = t & 15;
    const int bq = t >> 4;
    const int b = blockIdx.y * BT_OLD + bq;
    const int i0 = blockIdx.x * IT_OLD;
    float acc[JJ];
#pragma unroll
    for (int j = 0; j < JJ; ++j) acc[j] = 0.f;
    for (int ii = 0; ii < IT_OLD; ++ii) {
        const int i = i0 + ii;
        const float* xp = x + ((b * II) + i) * KK;
        const float4 xa = *(const float4*)(xp);
        const float4 xb = *(const float4*)(xp + 4);
#pragma unroll
        for (int j = 0; j < JJ; ++j) {
            const float* wp = W + (((j * II + i) * DD + d) * KK);
            const float4 w0 = *(const float4*)(wp);
            const float4 w1 = *(const float4*)(wp + 4);
            acc[j] += w0.x*xa.x + w0.y*xa.y + w0.z*xa.z + w0.w*xa.w
                    + w1.x*xb.x + w1.y*xb.y + w1.z*xb.z + w1.w*xb.w;
        }
    }
#pragma unroll
    for (int j = 0; j < JJ; ++j)
        atomicAdd(&s_acc[(b * JJ + j) * DD + d], acc[j]);
}

__global__ __launch_bounds__(256) void round_old(const float* __restrict__ x,
                                                 const float* __restrict__ W,
                                                 const float* __restrict__ v,
                                                 float* __restrict__ s_acc) {
    const int t = threadIdx.x;
    const int d = t & 15;
    const int bq = t >> 4;
    const int b = blockIdx.y * BT_OLD + bq;
    const int i0 = blockIdx.x * IT_OLD;
    float vr[JJ], acc[JJ];
#pragma unroll
    for (int j = 0; j < JJ; ++j) {
        vr[j] = v[(b * JJ + j) * DD + d];
        acc[j] = 0.f;
    }
    for (int ii = 0; ii < IT_OLD; ++ii) {
        const int i = i0 + ii;
        const float* xp = x + ((b * II) + i) * KK;
        const float4 xa = *(const float4*)(xp);
        const float4 xb = *(const float4*)(xp + 4);
        float U[JJ], Lg[JJ];
#pragma unroll
        for (int j = 0; j < JJ; ++j) {
            const float* wp = W + (((j * II + i) * DD + d) * KK);
            const float4 w0 = *(const float4*)(wp);
            const float4 w1 = *(const float4*)(wp + 4);
            U[j] = w0.x*xa.x + w0.y*xa.y + w0.z*xa.z + w0.w*xa.w
                 + w1.x*xb.x + w1.y*xb.y + w1.z*xb.z + w1.w*xb.w;
            Lg[j] = vr[j] * U[j];
        }
#pragma unroll
        for (int m = 8; m >= 1; m >>= 1) {
#pragma unroll
            for (int j = 0; j < JJ; ++j) Lg[j] += __shfl_xor(Lg[j], m, 64);
        }
        float mx = Lg[0];
#pragma unroll
        for (int j = 1; j < JJ; ++j) mx = fmaxf(mx, Lg[j]);
        float sum = 0.f;
#pragma unroll
        for (int j = 0; j < JJ; ++j) { Lg[j] = __expf(Lg[j] - mx); sum += Lg[j]; }
        const float inv = 1.f / sum;
#pragma unroll
        for (int j = 0; j < JJ; ++j) acc[j] += (Lg[j] * inv) * U[j];
    }
#pragma unroll
    for (int j = 0; j < JJ; ++j)
        atomicAdd(&s_acc[(b * JJ + j) * DD + d], acc[j]);
}

extern "C" void kernel_launch(void* const* d_in, const int* in_sizes, int n_in,
                              void* d_out, int out_size, void* d_ws, size_t ws_size,
                              hipStream_t stream) {
    const float* x = (const float*)d_in[0];   // [B, I, K]
    const float* W = (const float*)d_in[1];   // [J, I, D, K]
    float* out = (float*)d_out;               // [B, J, D]

    float* vT     = (float*)d_ws;                          // 40960 f32, layout [j][d][b]
    _Float16* p   = (_Float16*)(vT + BB * JJ * DD);        // 16*128*2560 f16
    short* xTb    = (short*)(p + (size_t)16 * 128 * 2560); // I*B*K bf16
    short* Wb     = xTb + (size_t)II * BB * KK;            // J*I*D*K bf16
    const size_t need = (size_t)(BB * JJ * DD) * 4
                      + (size_t)16 * 128 * 2560 * 2
                      + ((size_t)II * BB * KK + (size_t)JJ * II * DD * KK) * 2;

    if (ws_size >= need) {
        pre_kernel<<<1280 + 2048, 256, 0, stream>>>(x, W, xTb, Wb);

        dim3 rg(128, 4);
        dim3 sg(JJ, 16);
        // round 1: uniform c (1/J folded into squash scale)
        round_mfma<0><<<rg, 256, 0, stream>>>(xTb, Wb, vT, p);
        rs_kernel<0><<<sg, 512, 0, stream>>>(p, vT, out, 0.1f);
        // round 2: logits = v1 . U
        round_mfma<1><<<rg, 256, 0, stream>>>(xTb, Wb, vT, p);
        rs_kernel<1><<<sg, 512, 0, stream>>>(p, vT, out, 1.0f);
        // round 3: logits = (v1+v2) . U
        round_mfma<1><<<rg, 256, 0, stream>>>(xTb, Wb, vT, p);
        rs_kernel<2><<<sg, 512, 0, stream>>>(p, vT, out, 1.0f);
    } else {
        // fallback: round-1 passing path
        float* s_acc = (float*)d_ws;
        float* v_buf = s_acc + BB * JJ * DD;
        const int NS = BB * JJ * DD;
        dim3 rg(II / IT_OLD, BB / BT_OLD);
        zero_kernel<<<(NS + 255) / 256, 256, 0, stream>>>(s_acc, NS);
        round1_old<<<rg, 256, 0, stream>>>(x, W, s_acc);
        squash_old<<<(BB * JJ + 255) / 256, 256, 0, stream>>>(s_acc, v_buf, 0.1f, 0, 1);
        round_old<<<rg, 256, 0, stream>>>(x, W, v_buf, s_acc);
        squash_old<<<(BB * JJ + 255) / 256, 256, 0, stream>>>(s_acc, v_buf, 1.0f, 1, 1);
        round_old<<<rg, 256, 0, stream>>>(x, W, v_buf, s_acc);
        squash_old<<<(BB * JJ + 255) / 256, 256, 0, stream>>>(s_acc, out, 1.0f, 0, 0);
    }
}